// Round 11
// baseline (430.057 us; speedup 1.0000x reference)
//
#include <hip/hip_runtime.h>
#include <cstddef>

namespace {
constexpr int kB = 4;
constexpr int kS = 4096;
constexpr int kD = 64;
constexpr float kC = 0.18033688011112042f;  // (1/8) * log2(e) : exp(s/8) = exp2(s*kC)

typedef float  f32x4  __attribute__((ext_vector_type(4)));
typedef __bf16 bf16x8 __attribute__((ext_vector_type(8)));
typedef short  s16x2  __attribute__((ext_vector_type(2)));
typedef short  s16x4  __attribute__((ext_vector_type(4)));
typedef short  s16x8  __attribute__((ext_vector_type(8)));
typedef int    i32x4  __attribute__((ext_vector_type(4)));

constexpr size_t kWsQ = (size_t)kB * kS * kD;         // elements (bf16/short)
constexpr size_t kWsNeed = 3 * kWsQ * sizeof(short);  // 6.29 MB
}

// __bf16 scalar is trivially copyable -> bit_cast legal. (__bf16)f rounds RNE.
__device__ __forceinline__ s16x2 pack_bf16(float a, float b) {
    __bf16 ha = (__bf16)a, hb = (__bf16)b;
    s16x2 r;
    r.x = __builtin_bit_cast(short, ha);
    r.y = __builtin_bit_cast(short, hb);
    return r;
}

// ============================ pre-pass ====================================
// blocks [0,256): Q -> bf16 row-major; [256,512): K -> bf16 row-major;
// [512,768): V -> bf16 TRANSPOSED per batch: vt[b][d][j]  (64 x 4096)
__global__ __launch_bounds__(256)
void prepass_kernel(const float* __restrict__ q, const float* __restrict__ k,
                    const float* __restrict__ v, short* __restrict__ qb,
                    short* __restrict__ kb, short* __restrict__ vt)
{
    __shared__ float lt[64][65];
    const int bid = blockIdx.x, tid = threadIdx.x;
    if (bid < 512) {
        const float* src = (bid < 256) ? q : k;
        short* dst = (bid < 256) ? qb : kb;
        const int base = (bid & 255) * 4096;
        #pragma unroll
        for (int c = 0; c < 4; ++c) {
            const int idx = base + c * 1024 + tid * 4;
            float4 f = *(const float4*)(src + idx);
            s16x4 o = __builtin_shufflevector(pack_bf16(f.x, f.y), pack_bf16(f.z, f.w), 0, 1, 2, 3);
            *(s16x4*)(dst + idx) = o;
        }
    } else {
        const int vb = bid - 512;
        const int b = vb >> 6, j0 = (vb & 63) * 64;
        const int r = tid >> 2, seg = tid & 3;
        const float* vrow = v + ((size_t)(b * kS) + j0 + r) * kD + seg * 16;
        #pragma unroll
        for (int u = 0; u < 4; ++u) {
            float4 f = *(const float4*)(vrow + 4 * u);
            lt[r][seg * 16 + 4 * u + 0] = f.x;
            lt[r][seg * 16 + 4 * u + 1] = f.y;
            lt[r][seg * 16 + 4 * u + 2] = f.z;
            lt[r][seg * 16 + 4 * u + 3] = f.w;
        }
        __syncthreads();
        const int d = r, js = seg * 16;
        short* drow = vt + ((size_t)(b * kD) + d) * kS + j0 + js;
        #pragma unroll
        for (int w = 0; w < 4; ++w) {
            s16x4 o = __builtin_shufflevector(
                pack_bf16(lt[js + 4 * w + 0][d], lt[js + 4 * w + 1][d]),
                pack_bf16(lt[js + 4 * w + 2][d], lt[js + 4 * w + 3][d]), 0, 1, 2, 3);
            *(s16x4*)(drow + 4 * w) = o;
        }
    }
}

// ============================ main MFMA kernel (fused, R11) ================
// Block = 512 thr (8 waves), 16 Q rows; wave w handles j-slice [w*512,...).
// R11: re-fused R5's two passes so the kernel rises above the 168 µs
// harness-fill floor in rocprof top-5 (the split kernels were invisible ->
// no counters). Loop 2 is the R7 direct-store version: swapped MFMA operands
// put C in store orientation (lane (t,q) holds S[i0+4q+r][j0+t]) -> no LDS
// staging, no shuffles, no lgkm drains in the store loop. Plain (non-nt)
// stores: 64B segments/lane-group; adjacent j0 tiles merge in L2.
// A/B vs R2-fused (202 µs, LDS 35840, bankconf 3.1M): if loop-2 LDS was the
// cost, dur drops; if dur ~200 with bankconf ~0.3M, loop 1 owns the time.
__global__ __launch_bounds__(512, 8)
void attn_mfma_kernel(const short* __restrict__ qb, const short* __restrict__ kb,
                      const short* __restrict__ vt, float* __restrict__ outg,
                      float* __restrict__ attng)
{
    __shared__ __align__(16) float lds_out[7][16][68];  // 30464 B
    __shared__ float lds_rs[8][16];
    __shared__ float lds_linv[16];

    // XCD swizzle: 1024 blocks % 8 XCDs == 0 -> bijective.
    const int swz = (blockIdx.x & 7) * 128 + (blockIdx.x >> 3);
    const int b  = swz >> 8;
    const int i0 = (swz & 255) * 16;
    const int lane = threadIdx.x & 63;
    const int wave = threadIdx.x >> 6;   // 0..7
    const int t = lane & 15;
    const int q = lane >> 4;

    const short* Qb = qb + ((size_t)(b * kS) + i0) * kD;
    const short* Kb = kb + (size_t)(b * kS) * kD;
    const short* Vt = vt + (size_t)b * kD * kS;

    // Q fragments: persistent; used as B-operand in loop1, A-operand in loop2
    const bf16x8 qf0 = *(const bf16x8*)(Qb + t * kD + 8 * q);
    const bf16x8 qf1 = *(const bf16x8*)(Qb + t * kD + 32 + 8 * q);

    const int jbeg = wave * (kS / 8);
    const int jend = jbeg + (kS / 8);
    const int sA = t + 32 * (q & 1);  // shuffle source lane A (B = sA+16)

    f32x4 oacc[4];
    #pragma unroll
    for (int dt = 0; dt < 4; ++dt) oacc[dt] = (f32x4){0.f, 0.f, 0.f, 0.f};
    float rs = 0.f;

    // -------- loop 1: row sums + unnormalized P*V, 32 j's/iter -------------
    for (int j0 = jbeg; j0 < jend; j0 += 32) {
        int p0 = 0, p1 = 0, p2 = 0, p3 = 0;
        #pragma unroll
        for (int h = 0; h < 2; ++h) {
            const short* p = Kb + (size_t)(j0 + 16 * h + t) * kD + 8 * q;
            const bf16x8 ka0 = *(const bf16x8*)p;
            const bf16x8 ka1 = *(const bf16x8*)(p + 32);
            f32x4 acc = (f32x4){0.f, 0.f, 0.f, 0.f};
            acc = __builtin_amdgcn_mfma_f32_16x16x32_bf16(ka0, qf0, acc, 0, 0, 0);
            acc = __builtin_amdgcn_mfma_f32_16x16x32_bf16(ka1, qf1, acc, 0, 0, 0);
            const float e0 = __builtin_amdgcn_exp2f(acc[0] * kC);
            const float e1 = __builtin_amdgcn_exp2f(acc[1] * kC);
            const float e2 = __builtin_amdgcn_exp2f(acc[2] * kC);
            const float e3 = __builtin_amdgcn_exp2f(acc[3] * kC);
            rs += (e0 + e1) + (e2 + e3);
            const int d0 = __builtin_bit_cast(int, pack_bf16(e0, e1));
            const int d1 = __builtin_bit_cast(int, pack_bf16(e2, e3));
            const int a0 = __shfl(d0, sA);
            const int a1 = __shfl(d1, sA);
            const int b0 = __shfl(d0, sA + 16);
            const int b1 = __shfl(d1, sA + 16);
            if ((q >> 1) == h) { p0 = a0; p1 = a1; p2 = b0; p3 = b1; }
        }
        const i32x4 pi = (i32x4){p0, p1, p2, p3};
        const bf16x8 pa = __builtin_bit_cast(bf16x8, pi);

        #pragma unroll
        for (int dt = 0; dt < 4; ++dt) {
            const bf16x8 vb = *(const bf16x8*)(Vt + (size_t)(16 * dt + t) * kS + j0 + 8 * q);
            oacc[dt] = __builtin_amdgcn_mfma_f32_16x16x32_bf16(pa, vb, oacc[dt], 0, 0, 0);
        }
    }

    rs += __shfl_xor(rs, 16);
    rs += __shfl_xor(rs, 32);

    // -------- combine the 8 j-slices through LDS (2 barriers total) --------
    if (lane < 16) lds_rs[wave][t] = rs;
    if (wave > 0) {
        #pragma unroll
        for (int dt = 0; dt < 4; ++dt)
            #pragma unroll
            for (int r = 0; r < 4; ++r)
                lds_out[wave - 1][4 * q + r][16 * dt + t] = oacc[dt][r];
    }
    __syncthreads();
    if (wave == 0) {
        #pragma unroll
        for (int w = 0; w < 7; ++w)
            #pragma unroll
            for (int dt = 0; dt < 4; ++dt)
                #pragma unroll
                for (int r = 0; r < 4; ++r)
                    oacc[dt][r] += lds_out[w][4 * q + r][16 * dt + t];
        float tot = 0.f;
        #pragma unroll
        for (int w = 0; w < 8; ++w) tot += lds_rs[w][t];
        if (lane < 16) lds_linv[t] = 1.0f / tot;
    }
    __syncthreads();

    // out store (wave 0 only): lane holds out[i=i0+4q+r][dv=16dt+t]
    if (wave == 0) {
        #pragma unroll
        for (int r = 0; r < 4; ++r) {
            const float li = lds_linv[4 * q + r];
            float* orow = outg + ((size_t)(b * kS) + i0 + 4 * q + r) * kD + t;
            #pragma unroll
            for (int dt = 0; dt < 4; ++dt)
                orow[16 * dt] = oacc[dt][r] * li;
        }
    }

    // -------- loop 2: recompute scores (swapped operands), store direct ----
    // normalizers for the 4 output rows this lane stores: i0+4q+r
    const float l0 = lds_linv[4 * q + 0];
    const float l1 = lds_linv[4 * q + 1];
    const float l2 = lds_linv[4 * q + 2];
    const float l3 = lds_linv[4 * q + 3];

    float* a0 = attng + ((size_t)(b * kS) + i0 + 4 * q + 0) * kS + t;
    float* a1 = attng + ((size_t)(b * kS) + i0 + 4 * q + 1) * kS + t;
    float* a2 = attng + ((size_t)(b * kS) + i0 + 4 * q + 2) * kS + t;
    float* a3 = attng + ((size_t)(b * kS) + i0 + 4 * q + 3) * kS + t;

    #pragma unroll 2
    for (int j0 = jbeg; j0 < jend; j0 += 16) {
        const short* p = Kb + (size_t)(j0 + t) * kD + 8 * q;
        const bf16x8 ka0 = *(const bf16x8*)p;
        const bf16x8 ka1 = *(const bf16x8*)(p + 32);
        f32x4 acc = (f32x4){0.f, 0.f, 0.f, 0.f};
        acc = __builtin_amdgcn_mfma_f32_16x16x32_bf16(qf0, ka0, acc, 0, 0, 0);
        acc = __builtin_amdgcn_mfma_f32_16x16x32_bf16(qf1, ka1, acc, 0, 0, 0);
        // lane holds S[i0+4q+r][j0+t]; per-row normalize, store direct
        const float o0 = __builtin_amdgcn_exp2f(acc[0] * kC) * l0;
        const float o1 = __builtin_amdgcn_exp2f(acc[1] * kC) * l1;
        const float o2 = __builtin_amdgcn_exp2f(acc[2] * kC) * l2;
        const float o3 = __builtin_amdgcn_exp2f(acc[3] * kC) * l3;
        a0[j0] = o0;
        a1[j0] = o1;
        a2[j0] = o2;
        a3[j0] = o3;
    }
}

// ======================= fp32 fallback (R1 kernel, passed) =================
namespace fb {
constexpr int QT = 64, JT = 64;
constexpr float kScale = 0.125f;
constexpr int LP = kD + 4;
}
__global__ __launch_bounds__(256, 1)
void attn_fp32_kernel(const float* __restrict__ qg, const float* __restrict__ kg,
                      const float* __restrict__ vg, float* __restrict__ outg,
                      float* __restrict__ attng)
{
    using namespace fb;
    __shared__ float qs[QT][LP];
    __shared__ float ks[JT][LP];
    __shared__ float es[QT][JT + 4];
    __shared__ float red[QT][17];
    __shared__ float linv[QT];
    const int tid = threadIdx.x;
    const int tx = tid & 15, ty = tid >> 4;
    const int b = blockIdx.x >> 6, qt = blockIdx.x & 63, i0 = qt * QT;
    const float* qbp = qg + ((size_t)b * kS + i0) * kD;
    const float* kbase = kg + (size_t)b * kS * kD;
    const float* vbase = vg + (size_t)b * kS * kD;
    {
        const int r = tid >> 4, c4 = (tid & 15) * 4;
        #pragma unroll
        for (int m = 0; m < 4; ++m)
            *(float4*)&qs[r + 16 * m][c4] = *(const float4*)(qbp + (r + 16 * m) * kD + c4);
    }
    float oacc[4][4]; float rsv[4];
    #pragma unroll
    for (int r = 0; r < 4; ++r) { rsv[r] = 0.f; for (int c = 0; c < 4; ++c) oacc[r][c] = 0.f; }
    for (int jt = 0; jt < kS / JT; ++jt) {
        const float* kt = kbase + (size_t)(jt * JT) * kD;
        const int r = tid >> 4, c4 = (tid & 15) * 4;
        #pragma unroll
        for (int m = 0; m < 4; ++m)
            *(float4*)&ks[r + 16 * m][c4] = *(const float4*)(kt + (r + 16 * m) * kD + c4);
        __syncthreads();
        float acc[4][4] = {{0.f}};
        #pragma unroll
        for (int d4 = 0; d4 < kD / 4; ++d4) {
            float4 qa[4], kav[4];
            #pragma unroll
            for (int r2 = 0; r2 < 4; ++r2) qa[r2] = *(const float4*)&qs[ty * 4 + r2][d4 * 4];
            #pragma unroll
            for (int c = 0; c < 4; ++c) kav[c] = *(const float4*)&ks[tx * 4 + c][d4 * 4];
            #pragma unroll
            for (int r2 = 0; r2 < 4; ++r2)
                #pragma unroll
                for (int c = 0; c < 4; ++c)
                    acc[r2][c] += qa[r2].x * kav[c].x + qa[r2].y * kav[c].y
                                + qa[r2].z * kav[c].z + qa[r2].w * kav[c].w;
        }
        #pragma unroll
        for (int r2 = 0; r2 < 4; ++r2) {
            float4 e4;
            e4.x = __expf(acc[r2][0] * kScale); e4.y = __expf(acc[r2][1] * kScale);
            e4.z = __expf(acc[r2][2] * kScale); e4.w = __expf(acc[r2][3] * kScale);
            rsv[r2] += (e4.x + e4.y) + (e4.z + e4.w);
            *(float4*)&es[ty * 4 + r2][tx * 4] = e4;
        }
        __syncthreads();
        const float* vt2 = vbase + (size_t)(jt * JT) * kD;
        #pragma unroll 4
        for (int j4 = 0; j4 < JT / 4; ++j4) {
            float4 vv[4], ea[4];
            #pragma unroll
            for (int n = 0; n < 4; ++n) vv[n] = *(const float4*)(vt2 + (size_t)(j4 * 4 + n) * kD + tx * 4);
            #pragma unroll
            for (int r2 = 0; r2 < 4; ++r2) ea[r2] = *(const float4*)&es[ty * 4 + r2][j4 * 4];
            #pragma unroll
            for (int r2 = 0; r2 < 4; ++r2) {
                oacc[r2][0] += ea[r2].x * vv[0].x + ea[r2].y * vv[1].x + ea[r2].z * vv[2].x + ea[r2].w * vv[3].x;
                oacc[r2][1] += ea[r2].x * vv[0].y + ea[r2].y * vv[1].y + ea[r2].z * vv[2].y + ea[r2].w * vv[3].y;
                oacc[r2][2] += ea[r2].x * vv[0].z + ea[r2].y * vv[1].z + ea[r2].z * vv[2].z + ea[r2].w * vv[3].z;
                oacc[r2][3] += ea[r2].x * vv[0].w + ea[r2].y * vv[1].w + ea[r2].z * vv[2].w + ea[r2].w * vv[3].w;
            }
        }
        __syncthreads();
    }
    #pragma unroll
    for (int r = 0; r < 4; ++r) red[ty * 4 + r][tx] = rsv[r];
    __syncthreads();
    if (tid < QT) {
        float s = 0.f;
        #pragma unroll
        for (int t2 = 0; t2 < 16; ++t2) s += red[tid][t2];
        linv[tid] = 1.0f / s;
    }
    __syncthreads();
    {
        float* ob = outg + ((size_t)b * kS + i0) * kD;
        #pragma unroll
        for (int r = 0; r < 4; ++r) {
            const int i = ty * 4 + r; const float li = linv[i];
            float4 o4; o4.x = oacc[r][0] * li; o4.y = oacc[r][1] * li;
            o4.z = oacc[r][2] * li; o4.w = oacc[r][3] * li;
            *(float4*)(ob + (size_t)i * kD + tx * 4) = o4;
        }
    }
    float* ab = attng + ((size_t)b * kS + i0) * kS;
    for (int jt = 0; jt < kS / JT; ++jt) {
        const float* kt = kbase + (size_t)(jt * JT) * kD;
        const int r = tid >> 4, c4 = (tid & 15) * 4;
        #pragma unroll
        for (int m = 0; m < 4; ++m)
            *(float4*)&ks[r + 16 * m][c4] = *(const float4*)(kt + (r + 16 * m) * kD + c4);
        __syncthreads();
        float acc[4][4] = {{0.f}};
        #pragma unroll
        for (int d4 = 0; d4 < kD / 4; ++d4) {
            float4 qa[4], kav[4];
            #pragma unroll
            for (int r2 = 0; r2 < 4; ++r2) qa[r2] = *(const float4*)&qs[ty * 4 + r2][d4 * 4];
            #pragma unroll
            for (int c = 0; c < 4; ++c) kav[c] = *(const float4*)&ks[tx * 4 + c][d4 * 4];
            #pragma unroll
            for (int r2 = 0; r2 < 4; ++r2)
                #pragma unroll
                for (int c = 0; c < 4; ++c)
                    acc[r2][c] += qa[r2].x * kav[c].x + qa[r2].y * kav[c].y
                                + qa[r2].z * kav[c].z + qa[r2].w * kav[c].w;
        }
        #pragma unroll
        for (int r2 = 0; r2 < 4; ++r2) {
            const int i = ty * 4 + r2; const float li = linv[i];
            float4 e4;
            e4.x = __expf(acc[r2][0] * kScale) * li; e4.y = __expf(acc[r2][1] * kScale) * li;
            e4.z = __expf(acc[r2][2] * kScale) * li; e4.w = __expf(acc[r2][3] * kScale) * li;
            *(float4*)(ab + (size_t)i * kS + jt * JT + tx * 4) = e4;
        }
        __syncthreads();
    }
}

extern "C" void kernel_launch(void* const* d_in, const int* in_sizes, int n_in,
                              void* d_out, int out_size, void* d_ws, size_t ws_size,
                              hipStream_t stream) {
    const float* q = (const float*)d_in[0];
    const float* k = (const float*)d_in[1];
    const float* v = (const float*)d_in[2];
    float* out  = (float*)d_out;                  // [4,4096,64]
    float* attn = out + (size_t)kB * kS * kD;     // [4,4096,4096]

    if (ws_size >= kWsNeed) {
        short* qb = (short*)d_ws;
        short* kbp = qb + kWsQ;
        short* vt = kbp + kWsQ;
        prepass_kernel<<<dim3(768), 256, 0, stream>>>(q, k, v, qb, kbp, vt);
        attn_mfma_kernel<<<dim3(kB * (kS / 16)), 512, 0, stream>>>(qb, kbp, vt, out, attn);
    } else {
        attn_fp32_kernel<<<dim3(kB * (kS / 64)), 256, 0, stream>>>(q, k, v, out, attn);
    }
}

// Round 12
// 415.624 us; speedup vs baseline: 1.0347x; 1.0347x over previous
//
#include <hip/hip_runtime.h>
#include <cstddef>

namespace {
constexpr int kB = 4;
constexpr int kS = 4096;
constexpr int kD = 64;
constexpr float kC = 0.18033688011112042f;  // (1/8) * log2(e) : exp(s/8) = exp2(s*kC)

typedef float  f32x4  __attribute__((ext_vector_type(4)));
typedef __bf16 bf16x8 __attribute__((ext_vector_type(8)));
typedef short  s16x2  __attribute__((ext_vector_type(2)));
typedef short  s16x4  __attribute__((ext_vector_type(4)));
typedef short  s16x8  __attribute__((ext_vector_type(8)));
typedef int    i32x4  __attribute__((ext_vector_type(4)));

constexpr size_t kWsQ = (size_t)kB * kS * kD;         // elements (bf16/short)
constexpr size_t kWsNeed = 3 * kWsQ * sizeof(short);  // 6.29 MB
}

// __bf16 scalar is trivially copyable -> bit_cast legal. (__bf16)f rounds RNE.
__device__ __forceinline__ s16x2 pack_bf16(float a, float b) {
    __bf16 ha = (__bf16)a, hb = (__bf16)b;
    s16x2 r;
    r.x = __builtin_bit_cast(short, ha);
    r.y = __builtin_bit_cast(short, hb);
    return r;
}

// ============================ pre-pass ====================================
// blocks [0,256): Q -> bf16 row-major; [256,512): K -> bf16 row-major;
// [512,768): V -> bf16 TRANSPOSED per batch: vt[b][d][j]  (64 x 4096)
__global__ __launch_bounds__(256)
void prepass_kernel(const float* __restrict__ q, const float* __restrict__ k,
                    const float* __restrict__ v, short* __restrict__ qb,
                    short* __restrict__ kb, short* __restrict__ vt)
{
    __shared__ float lt[64][65];
    const int bid = blockIdx.x, tid = threadIdx.x;
    if (bid < 512) {
        const float* src = (bid < 256) ? q : k;
        short* dst = (bid < 256) ? qb : kb;
        const int base = (bid & 255) * 4096;
        #pragma unroll
        for (int c = 0; c < 4; ++c) {
            const int idx = base + c * 1024 + tid * 4;
            float4 f = *(const float4*)(src + idx);
            s16x4 o = __builtin_shufflevector(pack_bf16(f.x, f.y), pack_bf16(f.z, f.w), 0, 1, 2, 3);
            *(s16x4*)(dst + idx) = o;
        }
    } else {
        const int vb = bid - 512;
        const int b = vb >> 6, j0 = (vb & 63) * 64;
        const int r = tid >> 2, seg = tid & 3;
        const float* vrow = v + ((size_t)(b * kS) + j0 + r) * kD + seg * 16;
        #pragma unroll
        for (int u = 0; u < 4; ++u) {
            float4 f = *(const float4*)(vrow + 4 * u);
            lt[r][seg * 16 + 4 * u + 0] = f.x;
            lt[r][seg * 16 + 4 * u + 1] = f.y;
            lt[r][seg * 16 + 4 * u + 2] = f.z;
            lt[r][seg * 16 + 4 * u + 3] = f.w;
        }
        __syncthreads();
        const int d = r, js = seg * 16;
        short* drow = vt + ((size_t)(b * kD) + d) * kS + j0 + js;
        #pragma unroll
        for (int w = 0; w < 4; ++w) {
            s16x4 o = __builtin_shufflevector(
                pack_bf16(lt[js + 4 * w + 0][d], lt[js + 4 * w + 1][d]),
                pack_bf16(lt[js + 4 * w + 2][d], lt[js + 4 * w + 3][d]), 0, 1, 2, 3);
            *(s16x4*)(drow + 4 * w) = o;
        }
    }
}

// ============================ main MFMA kernel (R12) =======================
// Block = 512 thr (8 waves), 16 Q rows; loop 1: wave w owns j-slice
// [w*512,(w+1)*512). R12 theory: six store structures all plateau at
// ~1.5 TB/s because ~16-32k concurrent row-streams emit only 64-256B per
// HBM page activation (activation-rate limit ~6-8 G/s x 256B = 1.5-2 TB/s;
// fillBuffer's sequential bursts hit 6.4 TB/s on the same memory). Fix:
// loop 2 processes 512-j chunks; all waves stage the 16x512 f32 tile in LDS
// (unioned with loop-1 combine buffer), then each wave streams 2 FULL ROWS
// x 2KB contiguous (2 x 1KB dwordx4 back-to-back), rows advancing
// sequentially across chunks -> page-sized bursts, ~8-32x fewer activations.
__global__ __launch_bounds__(512, 8)
void attn_mfma_kernel(const short* __restrict__ qb, const short* __restrict__ kb,
                      const short* __restrict__ vt, float* __restrict__ outg,
                      float* __restrict__ attng)
{
    constexpr int ST = 516;  // staging row stride (floats): 516%32=4 -> 2-way
                             // write conflicts (free, m136); b128 reads ~8-way
                             // but read volume is tiny.
    // pool: loop-1 combine partials (7*16*68 = 7616 f) UNION loop-2 staging
    // (16*516 = 8256 f). Disjoint in time (combine done before loop 2).
    __shared__ __align__(16) float pool[16 * ST];   // 33024 B
    __shared__ float lds_rs[8][16];
    __shared__ float lds_linv[16];   // NOT in pool: read throughout loop 2

    // XCD swizzle: 1024 blocks % 8 XCDs == 0 -> bijective.
    const int swz = (blockIdx.x & 7) * 128 + (blockIdx.x >> 3);
    const int b  = swz >> 8;
    const int i0 = (swz & 255) * 16;
    const int lane = threadIdx.x & 63;
    const int wave = threadIdx.x >> 6;   // 0..7
    const int t = lane & 15;
    const int q = lane >> 4;

    const short* Qb = qb + ((size_t)(b * kS) + i0) * kD;
    const short* Kb = kb + (size_t)(b * kS) * kD;
    const short* Vt = vt + (size_t)b * kD * kS;

    // Q fragments: persistent; B-operand in loop 1, A-operand in loop 2
    const bf16x8 qf0 = *(const bf16x8*)(Qb + t * kD + 8 * q);
    const bf16x8 qf1 = *(const bf16x8*)(Qb + t * kD + 32 + 8 * q);

    const int jbeg = wave * (kS / 8);
    const int jend = jbeg + (kS / 8);
    const int sA = t + 32 * (q & 1);  // shuffle source lane A (B = sA+16)

    f32x4 oacc[4];
    #pragma unroll
    for (int dt = 0; dt < 4; ++dt) oacc[dt] = (f32x4){0.f, 0.f, 0.f, 0.f};
    float rs = 0.f;

    // -------- loop 1: row sums + unnormalized P*V, 32 j's/iter -------------
    for (int j0 = jbeg; j0 < jend; j0 += 32) {
        int p0 = 0, p1 = 0, p2 = 0, p3 = 0;
        #pragma unroll
        for (int h = 0; h < 2; ++h) {
            const short* p = Kb + (size_t)(j0 + 16 * h + t) * kD + 8 * q;
            const bf16x8 ka0 = *(const bf16x8*)p;
            const bf16x8 ka1 = *(const bf16x8*)(p + 32);
            f32x4 acc = (f32x4){0.f, 0.f, 0.f, 0.f};
            acc = __builtin_amdgcn_mfma_f32_16x16x32_bf16(ka0, qf0, acc, 0, 0, 0);
            acc = __builtin_amdgcn_mfma_f32_16x16x32_bf16(ka1, qf1, acc, 0, 0, 0);
            const float e0 = __builtin_amdgcn_exp2f(acc[0] * kC);
            const float e1 = __builtin_amdgcn_exp2f(acc[1] * kC);
            const float e2 = __builtin_amdgcn_exp2f(acc[2] * kC);
            const float e3 = __builtin_amdgcn_exp2f(acc[3] * kC);
            rs += (e0 + e1) + (e2 + e3);
            const int d0 = __builtin_bit_cast(int, pack_bf16(e0, e1));
            const int d1 = __builtin_bit_cast(int, pack_bf16(e2, e3));
            const int a0 = __shfl(d0, sA);
            const int a1 = __shfl(d1, sA);
            const int b0 = __shfl(d0, sA + 16);
            const int b1 = __shfl(d1, sA + 16);
            if ((q >> 1) == h) { p0 = a0; p1 = a1; p2 = b0; p3 = b1; }
        }
        const i32x4 pi = (i32x4){p0, p1, p2, p3};
        const bf16x8 pa = __builtin_bit_cast(bf16x8, pi);

        #pragma unroll
        for (int dt = 0; dt < 4; ++dt) {
            const bf16x8 vb = *(const bf16x8*)(Vt + (size_t)(16 * dt + t) * kS + j0 + 8 * q);
            oacc[dt] = __builtin_amdgcn_mfma_f32_16x16x32_bf16(pa, vb, oacc[dt], 0, 0, 0);
        }
    }

    rs += __shfl_xor(rs, 16);
    rs += __shfl_xor(rs, 32);

    // -------- combine the 8 j-slices through LDS (2 barriers) --------------
    if (lane < 16) lds_rs[wave][t] = rs;
    if (wave > 0) {
        #pragma unroll
        for (int dt = 0; dt < 4; ++dt)
            #pragma unroll
            for (int r = 0; r < 4; ++r)
                pool[((wave - 1) * 16 + 4 * q + r) * 68 + 16 * dt + t] = oacc[dt][r];
    }
    __syncthreads();
    if (wave == 0) {
        #pragma unroll
        for (int w = 0; w < 7; ++w)
            #pragma unroll
            for (int dt = 0; dt < 4; ++dt)
                #pragma unroll
                for (int r = 0; r < 4; ++r)
                    oacc[dt][r] += pool[(w * 16 + 4 * q + r) * 68 + 16 * dt + t];
        float tot = 0.f;
        #pragma unroll
        for (int w = 0; w < 8; ++w) tot += lds_rs[w][t];
        if (lane < 16) lds_linv[t] = 1.0f / tot;
    }
    __syncthreads();

    // out store (wave 0 only): lane holds out[i=i0+4q+r][dv=16dt+t]
    if (wave == 0) {
        #pragma unroll
        for (int r = 0; r < 4; ++r) {
            const float li = lds_linv[4 * q + r];
            float* orow = outg + ((size_t)(b * kS) + i0 + 4 * q + r) * kD + t;
            #pragma unroll
            for (int dt = 0; dt < 4; ++dt)
                orow[16 * dt] = oacc[dt][r] * li;
        }
    }

    // -------- loop 2: 512-j chunks; stage 16x512 tile; 2KB bursts/row ------
    const float l0 = lds_linv[4 * q + 0];
    const float l1 = lds_linv[4 * q + 1];
    const float l2 = lds_linv[4 * q + 2];
    const float l3 = lds_linv[4 * q + 3];

    const int row0 = 2 * wave;           // this wave's 2 output rows
    float* grow0 = attng + ((size_t)(b * kS) + i0 + row0 + 0) * kS;
    float* grow1 = attng + ((size_t)(b * kS) + i0 + row0 + 1) * kS;

    for (int c = 0; c < 8; ++c) {
        const int jc = c * 512;
        const int jw = jc + wave * 64;   // this wave's 64-j sub-range
        #pragma unroll
        for (int m = 0; m < 4; ++m) {
            const int j0 = jw + 16 * m;
            // swapped operands: lane (t,q) holds S[i0+4q+r][j0+t]
            const short* p = Kb + (size_t)(j0 + t) * kD + 8 * q;
            const bf16x8 ka0 = *(const bf16x8*)p;
            const bf16x8 ka1 = *(const bf16x8*)(p + 32);
            f32x4 acc = (f32x4){0.f, 0.f, 0.f, 0.f};
            acc = __builtin_amdgcn_mfma_f32_16x16x32_bf16(qf0, ka0, acc, 0, 0, 0);
            acc = __builtin_amdgcn_mfma_f32_16x16x32_bf16(qf1, ka1, acc, 0, 0, 0);
            const int col = wave * 64 + 16 * m + t;
            pool[(4 * q + 0) * ST + col] = __builtin_amdgcn_exp2f(acc[0] * kC) * l0;
            pool[(4 * q + 1) * ST + col] = __builtin_amdgcn_exp2f(acc[1] * kC) * l1;
            pool[(4 * q + 2) * ST + col] = __builtin_amdgcn_exp2f(acc[2] * kC) * l2;
            pool[(4 * q + 3) * ST + col] = __builtin_amdgcn_exp2f(acc[3] * kC) * l3;
        }
        __syncthreads();  // staging tile complete
        // each wave streams its 2 rows: 2 x 1KB dwordx4 back-to-back per row
        {
            const f32x4 v00 = *(const f32x4*)&pool[(row0 + 0) * ST + 0   + lane * 4];
            const f32x4 v01 = *(const f32x4*)&pool[(row0 + 0) * ST + 256 + lane * 4];
            *(f32x4*)(grow0 + jc + 0   + lane * 4) = v00;
            *(f32x4*)(grow0 + jc + 256 + lane * 4) = v01;
            const f32x4 v10 = *(const f32x4*)&pool[(row0 + 1) * ST + 0   + lane * 4];
            const f32x4 v11 = *(const f32x4*)&pool[(row0 + 1) * ST + 256 + lane * 4];
            *(f32x4*)(grow1 + jc + 0   + lane * 4) = v10;
            *(f32x4*)(grow1 + jc + 256 + lane * 4) = v11;
        }
        __syncthreads();  // before next chunk overwrites staging
    }
}

// ======================= fp32 fallback (R1 kernel, passed) =================
namespace fb {
constexpr int QT = 64, JT = 64;
constexpr float kScale = 0.125f;
constexpr int LP = kD + 4;
}
__global__ __launch_bounds__(256, 1)
void attn_fp32_kernel(const float* __restrict__ qg, const float* __restrict__ kg,
                      const float* __restrict__ vg, float* __restrict__ outg,
                      float* __restrict__ attng)
{
    using namespace fb;
    __shared__ float qs[QT][LP];
    __shared__ float ks[JT][LP];
    __shared__ float es[QT][JT + 4];
    __shared__ float red[QT][17];
    __shared__ float linv[QT];
    const int tid = threadIdx.x;
    const int tx = tid & 15, ty = tid >> 4;
    const int b = blockIdx.x >> 6, qt = blockIdx.x & 63, i0 = qt * QT;
    const float* qbp = qg + ((size_t)b * kS + i0) * kD;
    const float* kbase = kg + (size_t)b * kS * kD;
    const float* vbase = vg + (size_t)b * kS * kD;
    {
        const int r = tid >> 4, c4 = (tid & 15) * 4;
        #pragma unroll
        for (int m = 0; m < 4; ++m)
            *(float4*)&qs[r + 16 * m][c4] = *(const float4*)(qbp + (r + 16 * m) * kD + c4);
    }
    float oacc[4][4]; float rsv[4];
    #pragma unroll
    for (int r = 0; r < 4; ++r) { rsv[r] = 0.f; for (int c = 0; c < 4; ++c) oacc[r][c] = 0.f; }
    for (int jt = 0; jt < kS / JT; ++jt) {
        const float* kt = kbase + (size_t)(jt * JT) * kD;
        const int r = tid >> 4, c4 = (tid & 15) * 4;
        #pragma unroll
        for (int m = 0; m < 4; ++m)
            *(float4*)&ks[r + 16 * m][c4] = *(const float4*)(kt + (r + 16 * m) * kD + c4);
        __syncthreads();
        float acc[4][4] = {{0.f}};
        #pragma unroll
        for (int d4 = 0; d4 < kD / 4; ++d4) {
            float4 qa[4], kav[4];
            #pragma unroll
            for (int r2 = 0; r2 < 4; ++r2) qa[r2] = *(const float4*)&qs[ty * 4 + r2][d4 * 4];
            #pragma unroll
            for (int c = 0; c < 4; ++c) kav[c] = *(const float4*)&ks[tx * 4 + c][d4 * 4];
            #pragma unroll
            for (int r2 = 0; r2 < 4; ++r2)
                #pragma unroll
                for (int c = 0; c < 4; ++c)
                    acc[r2][c] += qa[r2].x * kav[c].x + qa[r2].y * kav[c].y
                                + qa[r2].z * kav[c].z + qa[r2].w * kav[c].w;
        }
        #pragma unroll
        for (int r2 = 0; r2 < 4; ++r2) {
            float4 e4;
            e4.x = __expf(acc[r2][0] * kScale); e4.y = __expf(acc[r2][1] * kScale);
            e4.z = __expf(acc[r2][2] * kScale); e4.w = __expf(acc[r2][3] * kScale);
            rsv[r2] += (e4.x + e4.y) + (e4.z + e4.w);
            *(float4*)&es[ty * 4 + r2][tx * 4] = e4;
        }
        __syncthreads();
        const float* vt2 = vbase + (size_t)(jt * JT) * kD;
        #pragma unroll 4
        for (int j4 = 0; j4 < JT / 4; ++j4) {
            float4 vv[4], ea[4];
            #pragma unroll
            for (int n = 0; n < 4; ++n) vv[n] = *(const float4*)(vt2 + (size_t)(j4 * 4 + n) * kD + tx * 4);
            #pragma unroll
            for (int r2 = 0; r2 < 4; ++r2) ea[r2] = *(const float4*)&es[ty * 4 + r2][j4 * 4];
            #pragma unroll
            for (int r2 = 0; r2 < 4; ++r2) {
                oacc[r2][0] += ea[r2].x * vv[0].x + ea[r2].y * vv[1].x + ea[r2].z * vv[2].x + ea[r2].w * vv[3].x;
                oacc[r2][1] += ea[r2].x * vv[0].y + ea[r2].y * vv[1].y + ea[r2].z * vv[2].y + ea[r2].w * vv[3].y;
                oacc[r2][2] += ea[r2].x * vv[0].z + ea[r2].y * vv[1].z + ea[r2].z * vv[2].z + ea[r2].w * vv[3].z;
                oacc[r2][3] += ea[r2].x * vv[0].w + ea[r2].y * vv[1].w + ea[r2].z * vv[2].w + ea[r2].w * vv[3].w;
            }
        }
        __syncthreads();
    }
    #pragma unroll
    for (int r = 0; r < 4; ++r) red[ty * 4 + r][tx] = rsv[r];
    __syncthreads();
    if (tid < QT) {
        float s = 0.f;
        #pragma unroll
        for (int t2 = 0; t2 < 16; ++t2) s += red[tid][t2];
        linv[tid] = 1.0f / s;
    }
    __syncthreads();
    {
        float* ob = outg + ((size_t)b * kS + i0) * kD;
        #pragma unroll
        for (int r = 0; r < 4; ++r) {
            const int i = ty * 4 + r; const float li = linv[i];
            float4 o4; o4.x = oacc[r][0] * li; o4.y = oacc[r][1] * li;
            o4.z = oacc[r][2] * li; o4.w = oacc[r][3] * li;
            *(float4*)(ob + (size_t)i * kD + tx * 4) = o4;
        }
    }
    float* ab = attng + ((size_t)b * kS + i0) * kS;
    for (int jt = 0; jt < kS / JT; ++jt) {
        const float* kt = kbase + (size_t)(jt * JT) * kD;
        const int r = tid >> 4, c4 = (tid & 15) * 4;
        #pragma unroll
        for (int m = 0; m < 4; ++m)
            *(float4*)&ks[r + 16 * m][c4] = *(const float4*)(kt + (r + 16 * m) * kD + c4);
        __syncthreads();
        float acc[4][4] = {{0.f}};
        #pragma unroll
        for (int d4 = 0; d4 < kD / 4; ++d4) {
            float4 qa[4], kav[4];
            #pragma unroll
            for (int r2 = 0; r2 < 4; ++r2) qa[r2] = *(const float4*)&qs[ty * 4 + r2][d4 * 4];
            #pragma unroll
            for (int c = 0; c < 4; ++c) kav[c] = *(const float4*)&ks[tx * 4 + c][d4 * 4];
            #pragma unroll
            for (int r2 = 0; r2 < 4; ++r2)
                #pragma unroll
                for (int c = 0; c < 4; ++c)
                    acc[r2][c] += qa[r2].x * kav[c].x + qa[r2].y * kav[c].y
                                + qa[r2].z * kav[c].z + qa[r2].w * kav[c].w;
        }
        #pragma unroll
        for (int r2 = 0; r2 < 4; ++r2) {
            const int i = ty * 4 + r2; const float li = linv[i];
            float4 e4;
            e4.x = __expf(acc[r2][0] * kScale) * li; e4.y = __expf(acc[r2][1] * kScale) * li;
            e4.z = __expf(acc[r2][2] * kScale) * li; e4.w = __expf(acc[r2][3] * kScale) * li;
            *(float4*)(ab + (size_t)i * kS + jt * JT + tx * 4) = e4;
        }
        __syncthreads();
    }
}

extern "C" void kernel_launch(void* const* d_in, const int* in_sizes, int n_in,
                              void* d_out, int out_size, void* d_ws, size_t ws_size,
                              hipStream_t stream) {
    const float* q = (const float*)d_in[0];
    const float* k = (const float*)d_in[1];
    const float* v = (const float*)d_in[2];
    float* out  = (float*)d_out;                  // [4,4096,64]
    float* attn = out + (size_t)kB * kS * kD;     // [4,4096,4096]

    if (ws_size >= kWsNeed) {
        short* qb = (short*)d_ws;
        short* kbp = qb + kWsQ;
        short* vt = kbp + kWsQ;
        prepass_kernel<<<dim3(768), 256, 0, stream>>>(q, k, v, qb, kbp, vt);
        attn_mfma_kernel<<<dim3(kB * (kS / 16)), 512, 0, stream>>>(qb, kbp, vt, out, attn);
    } else {
        attn_fp32_kernel<<<dim3(kB * (kS / 64)), 256, 0, stream>>>(q, k, v, out, attn);
    }
}

// Round 14
// 411.444 us; speedup vs baseline: 1.0452x; 1.0102x over previous
//
#include <hip/hip_runtime.h>
#include <cstddef>

namespace {
constexpr int kB = 4;
constexpr int kS = 4096;
constexpr int kD = 64;
constexpr float kC = 0.18033688011112042f;  // (1/8) * log2(e) : exp(s/8) = exp2(s*kC)

typedef float  f32x4  __attribute__((ext_vector_type(4)));
typedef __bf16 bf16x8 __attribute__((ext_vector_type(8)));
typedef short  s16x2  __attribute__((ext_vector_type(2)));
typedef short  s16x4  __attribute__((ext_vector_type(4)));
typedef short  s16x8  __attribute__((ext_vector_type(8)));
typedef int    i32x4  __attribute__((ext_vector_type(4)));

constexpr size_t kWsQ = (size_t)kB * kS * kD;         // elements (bf16/short)
constexpr size_t kWsNeed = 3 * kWsQ * sizeof(short);  // 6.29 MB
}

// __bf16 scalar is trivially copyable -> bit_cast legal. (__bf16)f rounds RNE.
__device__ __forceinline__ s16x2 pack_bf16(float a, float b) {
    __bf16 ha = (__bf16)a, hb = (__bf16)b;
    s16x2 r;
    r.x = __builtin_bit_cast(short, ha);
    r.y = __builtin_bit_cast(short, hb);
    return r;
}

// ============================ pre-pass ====================================
// blocks [0,256): Q -> bf16 row-major; [256,512): K -> bf16 row-major;
// [512,768): V -> bf16 TRANSPOSED per batch: vt[b][d][j]  (64 x 4096)
__global__ __launch_bounds__(256)
void prepass_kernel(const float* __restrict__ q, const float* __restrict__ k,
                    const float* __restrict__ v, short* __restrict__ qb,
                    short* __restrict__ kb, short* __restrict__ vt)
{
    __shared__ float lt[64][65];
    const int bid = blockIdx.x, tid = threadIdx.x;
    if (bid < 512) {
        const float* src = (bid < 256) ? q : k;
        short* dst = (bid < 256) ? qb : kb;
        const int base = (bid & 255) * 4096;
        #pragma unroll
        for (int c = 0; c < 4; ++c) {
            const int idx = base + c * 1024 + tid * 4;
            float4 f = *(const float4*)(src + idx);
            s16x4 o = __builtin_shufflevector(pack_bf16(f.x, f.y), pack_bf16(f.z, f.w), 0, 1, 2, 3);
            *(s16x4*)(dst + idx) = o;
        }
    } else {
        const int vb = bid - 512;
        const int b = vb >> 6, j0 = (vb & 63) * 64;
        const int r = tid >> 2, seg = tid & 3;
        const float* vrow = v + ((size_t)(b * kS) + j0 + r) * kD + seg * 16;
        #pragma unroll
        for (int u = 0; u < 4; ++u) {
            float4 f = *(const float4*)(vrow + 4 * u);
            lt[r][seg * 16 + 4 * u + 0] = f.x;
            lt[r][seg * 16 + 4 * u + 1] = f.y;
            lt[r][seg * 16 + 4 * u + 2] = f.z;
            lt[r][seg * 16 + 4 * u + 3] = f.w;
        }
        __syncthreads();
        const int d = r, js = seg * 16;
        short* drow = vt + ((size_t)(b * kD) + d) * kS + j0 + js;
        #pragma unroll
        for (int w = 0; w < 4; ++w) {
            s16x4 o = __builtin_shufflevector(
                pack_bf16(lt[js + 4 * w + 0][d], lt[js + 4 * w + 1][d]),
                pack_bf16(lt[js + 4 * w + 2][d], lt[js + 4 * w + 3][d]), 0, 1, 2, 3);
            *(s16x4*)(drow + 4 * w) = o;
        }
    }
}

// ============================ main MFMA kernel (R13) =======================
// Block = 512 thr (8 waves), 16 Q rows; wave w owns j-slice [w*512,(w+1)*512).
// R13: after 7 null store-side experiments (202 +/- 6 us invariant), the
// anomaly is VGPR_Count=32 — __launch_bounds__(512,8) demanded 8 waves/SIMD,
// capping the allocator at ~64 VGPR (it squeezed to 32). With oacc(16) +
// Q-frags(8) + addresses there were NO registers for loads in flight: the
// K/V stream serialized on ~300-cyc L2 latency one load at a time. This
// explains all pipes idle at 78% occupancy, the invariance to store shape,
// and fillBuffer's 6.4 TB/s (no dependent loads). Fix: drop the min-wave
// bound (compiler free to use ~100+ VGPR) + unroll 2 so two iterations'
// loads overlap in registers. R0 proved ~7 waves/CU suffices for TLP;
// per-wave MLP is what was missing.
__global__ __launch_bounds__(512)
void attn_mfma_kernel(const short* __restrict__ qb, const short* __restrict__ kb,
                      const short* __restrict__ vt, float* __restrict__ outg,
                      float* __restrict__ attng)
{
    __shared__ __align__(16) float lds_out[7][16][68];  // 30464 B
    __shared__ float lds_rs[8][16];
    __shared__ float lds_linv[16];

    // XCD swizzle: 1024 blocks % 8 XCDs == 0 -> bijective.
    const int swz = (blockIdx.x & 7) * 128 + (blockIdx.x >> 3);
    const int b  = swz >> 8;
    const int i0 = (swz & 255) * 16;
    const int lane = threadIdx.x & 63;
    const int wave = threadIdx.x >> 6;   // 0..7
    const int t = lane & 15;
    const int q = lane >> 4;

    const short* Qb = qb + ((size_t)(b * kS) + i0) * kD;
    const short* Kb = kb + (size_t)(b * kS) * kD;
    const short* Vt = vt + (size_t)b * kD * kS;

    // Q fragments: persistent; B-operand in loop 1, A-operand in loop 2
    const bf16x8 qf0 = *(const bf16x8*)(Qb + t * kD + 8 * q);
    const bf16x8 qf1 = *(const bf16x8*)(Qb + t * kD + 32 + 8 * q);

    const int jbeg = wave * (kS / 8);
    const int jend = jbeg + (kS / 8);
    const int sA = t + 32 * (q & 1);  // shuffle source lane A (B = sA+16)

    f32x4 oacc[4];
    #pragma unroll
    for (int dt = 0; dt < 4; ++dt) oacc[dt] = (f32x4){0.f, 0.f, 0.f, 0.f};
    float rs = 0.f;

    // -------- loop 1: row sums + unnormalized P*V, 32 j's/iter -------------
    #pragma unroll 2
    for (int j0 = jbeg; j0 < jend; j0 += 32) {
        int p0 = 0, p1 = 0, p2 = 0, p3 = 0;
        #pragma unroll
        for (int h = 0; h < 2; ++h) {
            const short* p = Kb + (size_t)(j0 + 16 * h + t) * kD + 8 * q;
            const bf16x8 ka0 = *(const bf16x8*)p;
            const bf16x8 ka1 = *(const bf16x8*)(p + 32);
            f32x4 acc = (f32x4){0.f, 0.f, 0.f, 0.f};
            acc = __builtin_amdgcn_mfma_f32_16x16x32_bf16(ka0, qf0, acc, 0, 0, 0);
            acc = __builtin_amdgcn_mfma_f32_16x16x32_bf16(ka1, qf1, acc, 0, 0, 0);
            const float e0 = __builtin_amdgcn_exp2f(acc[0] * kC);
            const float e1 = __builtin_amdgcn_exp2f(acc[1] * kC);
            const float e2 = __builtin_amdgcn_exp2f(acc[2] * kC);
            const float e3 = __builtin_amdgcn_exp2f(acc[3] * kC);
            rs += (e0 + e1) + (e2 + e3);
            const int d0 = __builtin_bit_cast(int, pack_bf16(e0, e1));
            const int d1 = __builtin_bit_cast(int, pack_bf16(e2, e3));
            const int a0 = __shfl(d0, sA);
            const int a1 = __shfl(d1, sA);
            const int b0 = __shfl(d0, sA + 16);
            const int b1 = __shfl(d1, sA + 16);
            if ((q >> 1) == h) { p0 = a0; p1 = a1; p2 = b0; p3 = b1; }
        }
        const i32x4 pi = (i32x4){p0, p1, p2, p3};
        const bf16x8 pa = __builtin_bit_cast(bf16x8, pi);

        #pragma unroll
        for (int dt = 0; dt < 4; ++dt) {
            const bf16x8 vb = *(const bf16x8*)(Vt + (size_t)(16 * dt + t) * kS + j0 + 8 * q);
            oacc[dt] = __builtin_amdgcn_mfma_f32_16x16x32_bf16(pa, vb, oacc[dt], 0, 0, 0);
        }
    }

    rs += __shfl_xor(rs, 16);
    rs += __shfl_xor(rs, 32);

    // -------- combine the 8 j-slices through LDS (2 barriers total) --------
    if (lane < 16) lds_rs[wave][t] = rs;
    if (wave > 0) {
        #pragma unroll
        for (int dt = 0; dt < 4; ++dt)
            #pragma unroll
            for (int r = 0; r < 4; ++r)
                lds_out[wave - 1][4 * q + r][16 * dt + t] = oacc[dt][r];
    }
    __syncthreads();
    if (wave == 0) {
        #pragma unroll
        for (int w = 0; w < 7; ++w)
            #pragma unroll
            for (int dt = 0; dt < 4; ++dt)
                #pragma unroll
                for (int r = 0; r < 4; ++r)
                    oacc[dt][r] += lds_out[w][4 * q + r][16 * dt + t];
        float tot = 0.f;
        #pragma unroll
        for (int w = 0; w < 8; ++w) tot += lds_rs[w][t];
        if (lane < 16) lds_linv[t] = 1.0f / tot;
    }
    __syncthreads();

    // out store (wave 0 only): lane holds out[i=i0+4q+r][dv=16dt+t]
    if (wave == 0) {
        #pragma unroll
        for (int r = 0; r < 4; ++r) {
            const float li = lds_linv[4 * q + r];
            float* orow = outg + ((size_t)(b * kS) + i0 + 4 * q + r) * kD + t;
            #pragma unroll
            for (int dt = 0; dt < 4; ++dt)
                orow[16 * dt] = oacc[dt][r] * li;
        }
    }

    // -------- loop 2: recompute scores (swapped operands), store direct ----
    const float l0 = lds_linv[4 * q + 0];
    const float l1 = lds_linv[4 * q + 1];
    const float l2 = lds_linv[4 * q + 2];
    const float l3 = lds_linv[4 * q + 3];

    float* a0 = attng + ((size_t)(b * kS) + i0 + 4 * q + 0) * kS + t;
    float* a1 = attng + ((size_t)(b * kS) + i0 + 4 * q + 1) * kS + t;
    float* a2 = attng + ((size_t)(b * kS) + i0 + 4 * q + 2) * kS + t;
    float* a3 = attng + ((size_t)(b * kS) + i0 + 4 * q + 3) * kS + t;

    #pragma unroll 4
    for (int j0 = jbeg; j0 < jend; j0 += 16) {
        const short* p = Kb + (size_t)(j0 + t) * kD + 8 * q;
        const bf16x8 ka0 = *(const bf16x8*)p;
        const bf16x8 ka1 = *(const bf16x8*)(p + 32);
        f32x4 acc = (f32x4){0.f, 0.f, 0.f, 0.f};
        acc = __builtin_amdgcn_mfma_f32_16x16x32_bf16(qf0, ka0, acc, 0, 0, 0);
        acc = __builtin_amdgcn_mfma_f32_16x16x32_bf16(qf1, ka1, acc, 0, 0, 0);
        // lane holds S[i0+4q+r][j0+t]; per-row normalize, store direct
        const float o0 = __builtin_amdgcn_exp2f(acc[0] * kC) * l0;
        const float o1 = __builtin_amdgcn_exp2f(acc[1] * kC) * l1;
        const float o2 = __builtin_amdgcn_exp2f(acc[2] * kC) * l2;
        const float o3 = __builtin_amdgcn_exp2f(acc[3] * kC) * l3;
        a0[j0] = o0;
        a1[j0] = o1;
        a2[j0] = o2;
        a3[j0] = o3;
    }
}

// ======================= fp32 fallback (R1 kernel, passed) =================
namespace fb {
constexpr int QT = 64, JT = 64;
constexpr float kScale = 0.125f;
constexpr int LP = kD + 4;
}
__global__ __launch_bounds__(256, 1)
void attn_fp32_kernel(const float* __restrict__ qg, const float* __restrict__ kg,
                      const float* __restrict__ vg, float* __restrict__ outg,
                      float* __restrict__ attng)
{
    using namespace fb;
    __shared__ float qs[QT][LP];
    __shared__ float ks[JT][LP];
    __shared__ float es[QT][JT + 4];
    __shared__ float red[QT][17];
    __shared__ float linv[QT];
    const int tid = threadIdx.x;
    const int tx = tid & 15, ty = tid >> 4;
    const int b = blockIdx.x >> 6, qt = blockIdx.x & 63, i0 = qt * QT;
    const float* qbp = qg + ((size_t)b * kS + i0) * kD;
    const float* kbase = kg + (size_t)b * kS * kD;
    const float* vbase = vg + (size_t)b * kS * kD;
    {
        const int r = tid >> 4, c4 = (tid & 15) * 4;
        #pragma unroll
        for (int m = 0; m < 4; ++m)
            *(float4*)&qs[r + 16 * m][c4] = *(const float4*)(qbp + (r + 16 * m) * kD + c4);
    }
    float oacc[4][4]; float rsv[4];
    #pragma unroll
    for (int r = 0; r < 4; ++r) { rsv[r] = 0.f; for (int c = 0; c < 4; ++c) oacc[r][c] = 0.f; }
    for (int jt = 0; jt < kS / JT; ++jt) {
        const float* kt = kbase + (size_t)(jt * JT) * kD;
        const int r = tid >> 4, c4 = (tid & 15) * 4;
        #pragma unroll
        for (int m = 0; m < 4; ++m)
            *(float4*)&ks[r + 16 * m][c4] = *(const float4*)(kt + (r + 16 * m) * kD + c4);
        __syncthreads();
        float acc[4][4] = {{0.f}};
        #pragma unroll
        for (int d4 = 0; d4 < kD / 4; ++d4) {
            float4 qa[4], kav[4];
            #pragma unroll
            for (int r2 = 0; r2 < 4; ++r2) qa[r2] = *(const float4*)&qs[ty * 4 + r2][d4 * 4];
            #pragma unroll
            for (int c = 0; c < 4; ++c) kav[c] = *(const float4*)&ks[tx * 4 + c][d4 * 4];
            #pragma unroll
            for (int r2 = 0; r2 < 4; ++r2)
                #pragma unroll
                for (int c = 0; c < 4; ++c)
                    acc[r2][c] += qa[r2].x * kav[c].x + qa[r2].y * kav[c].y
                                + qa[r2].z * kav[c].z + qa[r2].w * kav[c].w;
        }
        #pragma unroll
        for (int r2 = 0; r2 < 4; ++r2) {
            float4 e4;
            e4.x = __expf(acc[r2][0] * kScale); e4.y = __expf(acc[r2][1] * kScale);
            e4.z = __expf(acc[r2][2] * kScale); e4.w = __expf(acc[r2][3] * kScale);
            rsv[r2] += (e4.x + e4.y) + (e4.z + e4.w);
            *(float4*)&es[ty * 4 + r2][tx * 4] = e4;
        }
        __syncthreads();
        const float* vt2 = vbase + (size_t)(jt * JT) * kD;
        #pragma unroll 4
        for (int j4 = 0; j4 < JT / 4; ++j4) {
            float4 vv[4], ea[4];
            #pragma unroll
            for (int n = 0; n < 4; ++n) vv[n] = *(const float4*)(vt2 + (size_t)(j4 * 4 + n) * kD + tx * 4);
            #pragma unroll
            for (int r2 = 0; r2 < 4; ++r2) ea[r2] = *(const float4*)&es[ty * 4 + r2][j4 * 4];
            #pragma unroll
            for (int r2 = 0; r2 < 4; ++r2) {
                oacc[r2][0] += ea[r2].x * vv[0].x + ea[r2].y * vv[1].x + ea[r2].z * vv[2].x + ea[r2].w * vv[3].x;
                oacc[r2][1] += ea[r2].x * vv[0].y + ea[r2].y * vv[1].y + ea[r2].z * vv[2].y + ea[r2].w * vv[3].y;
                oacc[r2][2] += ea[r2].x * vv[0].z + ea[r2].y * vv[1].z + ea[r2].z * vv[2].z + ea[r2].w * vv[3].z;
                oacc[r2][3] += ea[r2].x * vv[0].w + ea[r2].y * vv[1].w + ea[r2].z * vv[2].w + ea[r2].w * vv[3].w;
            }
        }
        __syncthreads();
    }
    #pragma unroll
    for (int r = 0; r < 4; ++r) red[ty * 4 + r][tx] = rsv[r];
    __syncthreads();
    if (tid < QT) {
        float s = 0.f;
        #pragma unroll
        for (int t2 = 0; t2 < 16; ++t2) s += red[tid][t2];
        linv[tid] = 1.0f / s;
    }
    __syncthreads();
    {
        float* ob = outg + ((size_t)b * kS + i0) * kD;
        #pragma unroll
        for (int r = 0; r < 4; ++r) {
            const int i = ty * 4 + r; const float li = linv[i];
            float4 o4; o4.x = oacc[r][0] * li; o4.y = oacc[r][1] * li;
            o4.z = oacc[r][2] * li; o4.w = oacc[r][3] * li;
            *(float4*)(ob + (size_t)i * kD + tx * 4) = o4;
        }
    }
    float* ab = attng + ((size_t)b * kS + i0) * kS;
    for (int jt = 0; jt < kS / JT; ++jt) {
        const float* kt = kbase + (size_t)(jt * JT) * kD;
        const int r = tid >> 4, c4 = (tid & 15) * 4;
        #pragma unroll
        for (int m = 0; m < 4; ++m)
            *(float4*)&ks[r + 16 * m][c4] = *(const float4*)(kt + (r + 16 * m) * kD + c4);
        __syncthreads();
        float acc[4][4] = {{0.f}};
        #pragma unroll
        for (int d4 = 0; d4 < kD / 4; ++d4) {
            float4 qa[4], kav[4];
            #pragma unroll
            for (int r2 = 0; r2 < 4; ++r2) qa[r2] = *(const float4*)&qs[ty * 4 + r2][d4 * 4];
            #pragma unroll
            for (int c = 0; c < 4; ++c) kav[c] = *(const float4*)&ks[tx * 4 + c][d4 * 4];
            #pragma unroll
            for (int r2 = 0; r2 < 4; ++r2)
                #pragma unroll
                for (int c = 0; c < 4; ++c)
                    acc[r2][c] += qa[r2].x * kav[c].x + qa[r2].y * kav[c].y
                                + qa[r2].z * kav[c].z + qa[r2].w * kav[c].w;
        }
        #pragma unroll
        for (int r2 = 0; r2 < 4; ++r2) {
            const int i = ty * 4 + r2; const float li = linv[i];
            float4 e4;
            e4.x = __expf(acc[r2][0] * kScale) * li; e4.y = __expf(acc[r2][1] * kScale) * li;
            e4.z = __expf(acc[r2][2] * kScale) * li; e4.w = __expf(acc[r2][3] * kScale) * li;
            *(float4*)(ab + (size_t)i * kS + jt * JT + tx * 4) = e4;
        }
        __syncthreads();
    }
}

extern "C" void kernel_launch(void* const* d_in, const int* in_sizes, int n_in,
                              void* d_out, int out_size, void* d_ws, size_t ws_size,
                              hipStream_t stream) {
    const float* q = (const float*)d_in[0];
    const float* k = (const float*)d_in[1];
    const float* v = (const float*)d_in[2];
    float* out  = (float*)d_out;                  // [4,4096,64]
    float* attn = out + (size_t)kB * kS * kD;     // [4,4096,4096]

    if (ws_size >= kWsNeed) {
        short* qb = (short*)d_ws;
        short* kbp = qb + kWsQ;
        short* vt = kbp + kWsQ;
        prepass_kernel<<<dim3(768), 256, 0, stream>>>(q, k, v, qb, kbp, vt);
        attn_mfma_kernel<<<dim3(kB * (kS / 16)), 512, 0, stream>>>(qb, kbp, vt, out, attn);
    } else {
        attn_fp32_kernel<<<dim3(kB * (kS / 64)), 256, 0, stream>>>(q, k, v, out, attn);
    }
}